// Round 1
// baseline (169.208 us; speedup 1.0000x reference)
//
#include <hip/hip_runtime.h>
#include <hip/hip_bf16.h>
#include <stdint.h>

#define B 16
#define NN 2048
#define DIM 256
#define SZ 16384
#define TOPK 50
#define NCHUNK 32
#define CHUNK (NN / NCHUNK)  // 64

// ws layout (float offsets)
#define OFF_MEANB   0         // [B][DIM]
#define OFF_STDB    4096      // [B][DIM]
#define OFF_PSUM    8192      // [B][NCHUNK][DIM]
#define OFF_PSUMSQ  139264    // [B][NCHUNK][DIM]
#define OFF_DS      270336    // [B][SZ]
#define OFF_TOPD    532480    // [B][64]
#define OFF_TOPI    533504    // [B][64] (int)
#define OFF_A       534528    // [B][DIM]
#define OFF_C       538624    // [B][DIM]
// total 542720 floats = ~2.07 MB

__global__ __launch_bounds__(256) void k_partial(const float* __restrict__ x,
                                                 float* __restrict__ ws) {
    int b = blockIdx.y, c = blockIdx.x, d = threadIdx.x;
    const float* p = x + ((size_t)(b * NN + c * CHUNK)) * DIM + d;
    float s = 0.f, q = 0.f;
#pragma unroll 8
    for (int n = 0; n < CHUNK; n++) {
        float v = p[(size_t)n * DIM];
        s += v;
        q += v * v;
    }
    ws[OFF_PSUM + (b * NCHUNK + c) * DIM + d] = s;
    ws[OFF_PSUMSQ + (b * NCHUNK + c) * DIM + d] = q;
}

__global__ __launch_bounds__(256) void k_finalize(float* __restrict__ ws) {
    int b = blockIdx.x, d = threadIdx.x;
    float s = 0.f, q = 0.f;
#pragma unroll
    for (int c = 0; c < NCHUNK; c++) {
        s += ws[OFF_PSUM + (b * NCHUNK + c) * DIM + d];
        q += ws[OFF_PSUMSQ + (b * NCHUNK + c) * DIM + d];
    }
    float mean = s * (1.f / NN);
    float var = q * (1.f / NN) - mean * mean;
    float sd = sqrtf(fmaxf(var, 0.f));
    ws[OFF_MEANB + b * DIM + d] = mean;
    ws[OFF_STDB + b * DIM + d] = sd;
}

__global__ __launch_bounds__(256) void k_dist(const float* __restrict__ means,
                                              const float* __restrict__ stds,
                                              float* __restrict__ ws) {
    int tid = threadIdx.x;
    int b = tid & 15, el = tid >> 4;
    int e = blockIdx.x * 16 + el;
    const float4* m4 = (const float4*)means + (size_t)e * 64;
    const float4* s4 = (const float4*)stds + (size_t)e * 64;
    const float4* mb4 = (const float4*)(ws + OFF_MEANB) + b * 64;
    const float4* sb4 = (const float4*)(ws + OFF_STDB) + b * 64;
    float am = 0.f, as = 0.f;
#pragma unroll 4
    for (int k = 0; k < 64; k++) {
        float4 m = m4[k], mb = mb4[k];
        float dx = m.x - mb.x, dy = m.y - mb.y, dz = m.z - mb.z, dw = m.w - mb.w;
        am += dx * dx + dy * dy + dz * dz + dw * dw;
        float4 s = s4[k], sb = sb4[k];
        dx = s.x - sb.x; dy = s.y - sb.y; dz = s.z - sb.z; dw = s.w - sb.w;
        as += dx * dx + dy * dy + dz * dz + dw * dw;
    }
    float dsv = sqrtf(am) + sqrtf(as);
    __shared__ float t[16][17];
    t[b][el] = dsv;
    __syncthreads();
    int b2 = tid >> 4, el2 = tid & 15;
    ws[OFF_DS + b2 * SZ + blockIdx.x * 16 + el2] = t[b2][el2];
}

__global__ __launch_bounds__(256) void k_topk(float* __restrict__ ws) {
    int b = blockIdx.x, tid = threadIdx.x;
    const float* ds = ws + OFF_DS + b * SZ;
    __shared__ float rmin[256], rmax[256];
    __shared__ int hist[256];
    __shared__ int cum[256];
    __shared__ float sh_min, sh_scale;
    __shared__ int sh_T, sh_cnt;
    __shared__ float candV[1024];
    __shared__ int candI[1024];

    float mn = 1e30f, mx = -1e30f;
#pragma unroll 8
    for (int i = 0; i < 64; i++) {
        float v = ds[i * 256 + tid];
        mn = fminf(mn, v);
        mx = fmaxf(mx, v);
    }
    rmin[tid] = mn; rmax[tid] = mx;
    __syncthreads();
    for (int off = 128; off > 0; off >>= 1) {
        if (tid < off) {
            rmin[tid] = fminf(rmin[tid], rmin[tid + off]);
            rmax[tid] = fmaxf(rmax[tid], rmax[tid + off]);
        }
        __syncthreads();
    }
    if (tid == 0) {
        sh_min = rmin[0];
        sh_scale = 255.0f / fmaxf(rmax[0] - rmin[0], 1e-20f);
        sh_cnt = 0;
    }
    hist[tid] = 0;
    __syncthreads();

    float lo = sh_min, sc = sh_scale;
#pragma unroll 4
    for (int i = 0; i < 64; i++) {
        float v = ds[i * 256 + tid];
        int bin = (int)((v - lo) * sc);
        bin = min(max(bin, 0), 255);
        atomicAdd(&hist[bin], 1);
    }
    __syncthreads();

    // inclusive scan over 256 bins
    cum[tid] = hist[tid];
    __syncthreads();
    for (int off = 1; off < 256; off <<= 1) {
        int v = (tid >= off) ? cum[tid - off] : 0;
        __syncthreads();
        cum[tid] += v;
        __syncthreads();
    }
    if (cum[tid] >= TOPK && (tid == 0 || cum[tid - 1] < TOPK)) sh_T = tid;
    __syncthreads();
    int T = sh_T;

    // collect candidates (all true top-50 are in bins <= T)
#pragma unroll 4
    for (int i = 0; i < 64; i++) {
        float v = ds[i * 256 + tid];
        int bin = (int)((v - lo) * sc);
        bin = min(max(bin, 0), 255);
        if (bin <= T) {
            int p = atomicAdd(&sh_cnt, 1);
            if (p < 1024) { candV[p] = v; candI[p] = i * 256 + tid; }
        }
    }
    __syncthreads();
    int cnt = min(sh_cnt, 1024);
    if (tid >= 64) return;

    // exact selection on wave 0: key = (float-bits << 32) | index
    unsigned long long key[16];
#pragma unroll
    for (int j = 0; j < 16; j++) {
        int p = tid + j * 64;
        if (p < cnt) {
            unsigned int fb = __float_as_uint(candV[p]);
            key[j] = ((unsigned long long)fb << 32) | (unsigned int)candI[p];
        } else {
            key[j] = ~0ull;
        }
    }
    float* topd = ws + OFF_TOPD + b * 64;
    int* topi = (int*)(ws + OFF_TOPI) + b * 64;
    for (int r = 0; r < TOPK; r++) {
        unsigned long long m = key[0];
#pragma unroll
        for (int j = 1; j < 16; j++) m = (key[j] < m) ? key[j] : m;
#pragma unroll
        for (int off = 32; off > 0; off >>= 1) {
            unsigned long long o = __shfl_xor(m, off, 64);
            m = (o < m) ? o : m;
        }
        if (tid == 0) {
            topd[r] = __uint_as_float((unsigned int)(m >> 32));
            topi[r] = (int)(m & 0xffffffffu);
        }
#pragma unroll
        for (int j = 0; j < 16; j++)
            if (key[j] == m) key[j] = ~0ull;
    }
}

__global__ __launch_bounds__(256) void k_goal(const float* __restrict__ means,
                                              const float* __restrict__ stds,
                                              const float* __restrict__ t1p,
                                              const float* __restrict__ t2p,
                                              float* __restrict__ ws) {
    int b = blockIdx.x, d = threadIdx.x;
    float t1 = t1p[0], t2 = t2p[0];
    const float* topd = ws + OFF_TOPD + b * 64;
    const int* topi = (const int*)(ws + OFF_TOPI) + b * 64;
    float sum = 0.f;
#pragma unroll 10
    for (int r = 0; r < TOPK; r++) sum += expf(-t1 * topd[r]);
    float inv = 1.f / sum;
    float mg = 0.f, sg = 0.f;
    for (int r = 0; r < TOPK; r++) {
        float w = expf(-t1 * topd[r]) * inv;
        int idx = topi[r];
        mg += w * means[(size_t)idx * DIM + d];
        sg += w * stds[(size_t)idx * DIM + d];
    }
    float mean = ws[OFF_MEANB + b * DIM + d];
    float sd = ws[OFF_STDB + b * DIM + d];
    float lerp = 1.f / (1.f + expf(-t2));
    float mf = lerp * mg + (1.f - lerp) * mean;
    float sf = lerp * sg + (1.f - lerp) * sd;
    float A = sf / sd;
    float C = mf - A * mean;
    ws[OFF_A + b * DIM + d] = A;
    ws[OFF_C + b * DIM + d] = C;
}

__global__ __launch_bounds__(256) void k_apply(const float* __restrict__ x,
                                               const float* __restrict__ ws,
                                               float* __restrict__ out) {
    int f4 = blockIdx.x * 256 + threadIdx.x;  // float4 index, 0..2097151
    int b = f4 >> 17;                          // / (2048*64)
    int d4 = f4 & 63;
    float4 xv = ((const float4*)x)[f4];
    float4 a = ((const float4*)(ws + OFF_A))[b * 64 + d4];
    float4 c = ((const float4*)(ws + OFF_C))[b * 64 + d4];
    float4 o;
    o.x = fmaf(a.x, xv.x, c.x);
    o.y = fmaf(a.y, xv.y, c.y);
    o.z = fmaf(a.z, xv.z, c.z);
    o.w = fmaf(a.w, xv.w, c.w);
    ((float4*)out)[f4] = o;
}

extern "C" void kernel_launch(void* const* d_in, const int* in_sizes, int n_in,
                              void* d_out, int out_size, void* d_ws, size_t ws_size,
                              hipStream_t stream) {
    const float* x = (const float*)d_in[0];
    const float* means = (const float*)d_in[1];
    const float* stds = (const float*)d_in[2];
    const float* t1 = (const float*)d_in[3];
    const float* t2 = (const float*)d_in[4];
    float* out = (float*)d_out;
    float* ws = (float*)d_ws;

    k_partial<<<dim3(NCHUNK, B), 256, 0, stream>>>(x, ws);
    k_finalize<<<B, 256, 0, stream>>>(ws);
    k_dist<<<SZ / 16, 256, 0, stream>>>(means, stds, ws);
    k_topk<<<B, 256, 0, stream>>>(ws);
    k_goal<<<B, 256, 0, stream>>>(means, stds, t1, t2, ws);
    k_apply<<<(B * NN * DIM / 4) / 256, 256, 0, stream>>>(x, ws, out);
}

// Round 2
// 109.609 us; speedup vs baseline: 1.5437x; 1.5437x over previous
//
#include <hip/hip_runtime.h>
#include <hip/hip_bf16.h>
#include <stdint.h>

#define B 16
#define NN 2048
#define DIM 256
#define SZ 16384
#define TOPK 50
#define NCHUNK 32
#define CHUNK (NN / NCHUNK)  // 64

// ws layout (float offsets)
#define OFF_MEANB   0         // [B][DIM]
#define OFF_STDB    4096      // [B][DIM]
#define OFF_PSUM    8192      // [B][NCHUNK][DIM]
#define OFF_PSUMSQ  139264    // [B][NCHUNK][DIM]
#define OFF_DS      270336    // [B][SZ]
#define OFF_TOPD    532480    // [B][64]
#define OFF_TOPI    533504    // [B][64] (int)
#define OFF_A       534528    // [B][DIM]
#define OFF_C       538624    // [B][DIM]

__global__ __launch_bounds__(256) void k_partial(const float* __restrict__ x,
                                                 float* __restrict__ ws) {
    int b = blockIdx.y, c = blockIdx.x;
    int t = threadIdx.x;
    int rs = t >> 6, col = t & 63;
    const float4* p = (const float4*)x + ((size_t)(b * NN + c * CHUNK + rs)) * 64 + col;
    float4 s = {0.f, 0.f, 0.f, 0.f}, q = {0.f, 0.f, 0.f, 0.f};
#pragma unroll 4
    for (int n = 0; n < CHUNK / 4; n++) {  // rows rs, rs+4, ...
        float4 v = p[(size_t)n * 256];
        s.x += v.x; s.y += v.y; s.z += v.z; s.w += v.w;
        q.x += v.x * v.x; q.y += v.y * v.y; q.z += v.z * v.z; q.w += v.w * v.w;
    }
    __shared__ float4 ss[4][64], qq[4][64];
    ss[rs][col] = s; qq[rs][col] = q;
    __syncthreads();
    if (t < 64) {
        float4 S = ss[0][t], Q = qq[0][t];
#pragma unroll
        for (int r = 1; r < 4; r++) {
            float4 a = ss[r][t], b2 = qq[r][t];
            S.x += a.x; S.y += a.y; S.z += a.z; S.w += a.w;
            Q.x += b2.x; Q.y += b2.y; Q.z += b2.z; Q.w += b2.w;
        }
        ((float4*)(ws + OFF_PSUM))[(b * NCHUNK + c) * 64 + t] = S;
        ((float4*)(ws + OFF_PSUMSQ))[(b * NCHUNK + c) * 64 + t] = Q;
    }
}

__global__ __launch_bounds__(256) void k_finalize(float* __restrict__ ws) {
    int b = blockIdx.x, d = threadIdx.x;
    float s = 0.f, q = 0.f;
#pragma unroll
    for (int c = 0; c < NCHUNK; c++) {
        s += ws[OFF_PSUM + (b * NCHUNK + c) * DIM + d];
        q += ws[OFF_PSUMSQ + (b * NCHUNK + c) * DIM + d];
    }
    float mean = s * (1.f / NN);
    float var = q * (1.f / NN) - mean * mean;
    float sd = sqrtf(fmaxf(var, 0.f));
    ws[OFF_MEANB + b * DIM + d] = mean;
    ws[OFF_STDB + b * DIM + d] = sd;
}

#define RS_STEP(half)                                                   \
    {                                                                   \
        bool hi = (sub & half) != 0;                                    \
        _Pragma("unroll")                                               \
        for (int j = 0; j < half; j++) {                                \
            float send = hi ? am[j] : am[j + half];                     \
            float keep = hi ? am[j + half] : am[j];                     \
            am[j] = keep + __shfl_xor(send, half, 16);                  \
            send = hi ? as[j] : as[j + half];                           \
            keep = hi ? as[j + half] : as[j];                           \
            as[j] = keep + __shfl_xor(send, half, 16);                  \
        }                                                               \
    }

__global__ __launch_bounds__(256) void k_dist(const float* __restrict__ means,
                                              const float* __restrict__ stds,
                                              float* __restrict__ ws) {
    __shared__ float4 lm[16 * 64], ls[16 * 64];
    int tid = threadIdx.x;
    const float4* gm = (const float4*)(ws + OFF_MEANB);
    const float4* gs = (const float4*)(ws + OFF_STDB);
#pragma unroll
    for (int i = 0; i < 4; i++) {
        lm[i * 256 + tid] = gm[i * 256 + tid];
        ls[i * 256 + tid] = gs[i * 256 + tid];
    }
    __syncthreads();
    int lane = tid & 63, wid = tid >> 6;
    int sub = lane & 15, eg = lane >> 4;
    int e = blockIdx.x * 16 + wid * 4 + eg;
    const float4* mrow = (const float4*)means + (size_t)e * 64;
    const float4* srow = (const float4*)stds + (size_t)e * 64;
    float4 m[4], s[4];
#pragma unroll
    for (int k = 0; k < 4; k++) {
        m[k] = mrow[k * 16 + sub];   // contiguous 1KB per wave instr
        s[k] = srow[k * 16 + sub];
    }
    float am[16], as[16];
#pragma unroll
    for (int b = 0; b < 16; b++) {
        float accm = 0.f, accs = 0.f;
#pragma unroll
        for (int k = 0; k < 4; k++) {
            float4 q = lm[b * 64 + k * 16 + sub];
            float dx = m[k].x - q.x, dy = m[k].y - q.y;
            float dz = m[k].z - q.z, dw = m[k].w - q.w;
            accm += dx * dx + dy * dy + dz * dz + dw * dw;
            q = ls[b * 64 + k * 16 + sub];
            dx = s[k].x - q.x; dy = s[k].y - q.y;
            dz = s[k].z - q.z; dw = s[k].w - q.w;
            accs += dx * dx + dy * dy + dz * dz + dw * dw;
        }
        am[b] = accm; as[b] = accs;
    }
    // reduce-scatter within 16-lane groups: lane `sub` ends owning batch b==sub
    RS_STEP(8)
    RS_STEP(4)
    RS_STEP(2)
    RS_STEP(1)
    ws[OFF_DS + sub * SZ + e] = sqrtf(am[0]) + sqrtf(as[0]);
}

__global__ __launch_bounds__(256) void k_topk(float* __restrict__ ws) {
    int b = blockIdx.x, tid = threadIdx.x;
    const float* ds = ws + OFF_DS + b * SZ;
    __shared__ float rmin[256], rmax[256];
    __shared__ int hist[256];
    __shared__ int cum[256];
    __shared__ float sh_min, sh_scale;
    __shared__ int sh_T, sh_cnt;
    __shared__ float candV[1024];
    __shared__ int candI[1024];

    float mn = 1e30f, mx = -1e30f;
#pragma unroll 8
    for (int i = 0; i < 64; i++) {
        float v = ds[i * 256 + tid];
        mn = fminf(mn, v);
        mx = fmaxf(mx, v);
    }
    rmin[tid] = mn; rmax[tid] = mx;
    __syncthreads();
    for (int off = 128; off > 0; off >>= 1) {
        if (tid < off) {
            rmin[tid] = fminf(rmin[tid], rmin[tid + off]);
            rmax[tid] = fmaxf(rmax[tid], rmax[tid + off]);
        }
        __syncthreads();
    }
    if (tid == 0) {
        sh_min = rmin[0];
        sh_scale = 255.0f / fmaxf(rmax[0] - rmin[0], 1e-20f);
        sh_cnt = 0;
    }
    hist[tid] = 0;
    __syncthreads();

    float lo = sh_min, sc = sh_scale;
#pragma unroll 4
    for (int i = 0; i < 64; i++) {
        float v = ds[i * 256 + tid];
        int bin = (int)((v - lo) * sc);
        bin = min(max(bin, 0), 255);
        atomicAdd(&hist[bin], 1);
    }
    __syncthreads();

    cum[tid] = hist[tid];
    __syncthreads();
    for (int off = 1; off < 256; off <<= 1) {
        int v = (tid >= off) ? cum[tid - off] : 0;
        __syncthreads();
        cum[tid] += v;
        __syncthreads();
    }
    if (cum[tid] >= TOPK && (tid == 0 || cum[tid - 1] < TOPK)) sh_T = tid;
    __syncthreads();
    int T = sh_T;

#pragma unroll 4
    for (int i = 0; i < 64; i++) {
        float v = ds[i * 256 + tid];
        int bin = (int)((v - lo) * sc);
        bin = min(max(bin, 0), 255);
        if (bin <= T) {
            int p = atomicAdd(&sh_cnt, 1);
            if (p < 1024) { candV[p] = v; candI[p] = i * 256 + tid; }
        }
    }
    __syncthreads();
    int cnt = min(sh_cnt, 1024);
    if (tid >= 64) return;

    unsigned long long key[16];
#pragma unroll
    for (int j = 0; j < 16; j++) {
        int p = tid + j * 64;
        if (p < cnt) {
            unsigned int fb = __float_as_uint(candV[p]);
            key[j] = ((unsigned long long)fb << 32) | (unsigned int)candI[p];
        } else {
            key[j] = ~0ull;
        }
    }
    float* topd = ws + OFF_TOPD + b * 64;
    int* topi = (int*)(ws + OFF_TOPI) + b * 64;
    for (int r = 0; r < TOPK; r++) {
        unsigned long long m = key[0];
#pragma unroll
        for (int j = 1; j < 16; j++) m = (key[j] < m) ? key[j] : m;
#pragma unroll
        for (int off = 32; off > 0; off >>= 1) {
            unsigned long long o = __shfl_xor(m, off, 64);
            m = (o < m) ? o : m;
        }
        if (tid == 0) {
            topd[r] = __uint_as_float((unsigned int)(m >> 32));
            topi[r] = (int)(m & 0xffffffffu);
        }
#pragma unroll
        for (int j = 0; j < 16; j++)
            if (key[j] == m) key[j] = ~0ull;
    }
}

__global__ __launch_bounds__(256) void k_goal(const float* __restrict__ means,
                                              const float* __restrict__ stds,
                                              const float* __restrict__ t1p,
                                              const float* __restrict__ t2p,
                                              float* __restrict__ ws) {
    int b = blockIdx.x, d = threadIdx.x;
    float t1 = t1p[0], t2 = t2p[0];
    const float* topd = ws + OFF_TOPD + b * 64;
    const int* topi = (const int*)(ws + OFF_TOPI) + b * 64;
    float sum = 0.f;
#pragma unroll 10
    for (int r = 0; r < TOPK; r++) sum += expf(-t1 * topd[r]);
    float inv = 1.f / sum;
    float mg = 0.f, sg = 0.f;
#pragma unroll 5
    for (int r = 0; r < TOPK; r++) {
        float w = expf(-t1 * topd[r]) * inv;
        int idx = topi[r];
        mg += w * means[(size_t)idx * DIM + d];
        sg += w * stds[(size_t)idx * DIM + d];
    }
    float mean = ws[OFF_MEANB + b * DIM + d];
    float sd = ws[OFF_STDB + b * DIM + d];
    float lerp = 1.f / (1.f + expf(-t2));
    float mf = lerp * mg + (1.f - lerp) * mean;
    float sf = lerp * sg + (1.f - lerp) * sd;
    float A = sf / sd;
    float C = mf - A * mean;
    ws[OFF_A + b * DIM + d] = A;
    ws[OFF_C + b * DIM + d] = C;
}

__global__ __launch_bounds__(256) void k_apply(const float* __restrict__ x,
                                               const float* __restrict__ ws,
                                               float* __restrict__ out) {
    int f4 = blockIdx.x * 256 + threadIdx.x;
    int b = f4 >> 17;
    int d4 = f4 & 63;
    float4 xv = ((const float4*)x)[f4];
    float4 a = ((const float4*)(ws + OFF_A))[b * 64 + d4];
    float4 c = ((const float4*)(ws + OFF_C))[b * 64 + d4];
    float4 o;
    o.x = fmaf(a.x, xv.x, c.x);
    o.y = fmaf(a.y, xv.y, c.y);
    o.z = fmaf(a.z, xv.z, c.z);
    o.w = fmaf(a.w, xv.w, c.w);
    ((float4*)out)[f4] = o;
}

extern "C" void kernel_launch(void* const* d_in, const int* in_sizes, int n_in,
                              void* d_out, int out_size, void* d_ws, size_t ws_size,
                              hipStream_t stream) {
    const float* x = (const float*)d_in[0];
    const float* means = (const float*)d_in[1];
    const float* stds = (const float*)d_in[2];
    const float* t1 = (const float*)d_in[3];
    const float* t2 = (const float*)d_in[4];
    float* out = (float*)d_out;
    float* ws = (float*)d_ws;

    k_partial<<<dim3(NCHUNK, B), 256, 0, stream>>>(x, ws);
    k_finalize<<<B, 256, 0, stream>>>(ws);
    k_dist<<<SZ / 16, 256, 0, stream>>>(means, stds, ws);
    k_topk<<<B, 256, 0, stream>>>(ws);
    k_goal<<<B, 256, 0, stream>>>(means, stds, t1, t2, ws);
    k_apply<<<(B * NN * DIM / 4) / 256, 256, 0, stream>>>(x, ws, out);
}

// Round 3
// 70.565 us; speedup vs baseline: 2.3979x; 1.5533x over previous
//
#include <hip/hip_runtime.h>
#include <hip/hip_bf16.h>
#include <stdint.h>

#define B 16
#define NN 2048
#define DIM 256
#define SZ 16384
#define TOPK 50
#define NCHUNK 32
#define CHUNK (NN / NCHUNK)  // 64

// ws layout (float offsets)
#define OFF_MEANB   0         // [B][DIM]
#define OFF_STDB    4096      // [B][DIM]
#define OFF_PSUM    8192      // [B][NCHUNK][DIM]
#define OFF_PSUMSQ  139264    // [B][NCHUNK][DIM]
#define OFF_DS      270336    // [B][SZ]
#define OFF_TOPD    532480    // [B][64]
#define OFF_TOPI    533504    // [B][64] (int)
#define OFF_A       534528    // [B][DIM]
#define OFF_C       538624    // [B][DIM]

__global__ __launch_bounds__(256) void k_partial(const float* __restrict__ x,
                                                 float* __restrict__ ws) {
    int b = blockIdx.y, c = blockIdx.x;
    int t = threadIdx.x;
    int rs = t >> 6, col = t & 63;
    const float4* p = (const float4*)x + ((size_t)(b * NN + c * CHUNK + rs)) * 64 + col;
    float4 s = {0.f, 0.f, 0.f, 0.f}, q = {0.f, 0.f, 0.f, 0.f};
#pragma unroll 4
    for (int n = 0; n < CHUNK / 4; n++) {
        float4 v = p[(size_t)n * 256];
        s.x += v.x; s.y += v.y; s.z += v.z; s.w += v.w;
        q.x += v.x * v.x; q.y += v.y * v.y; q.z += v.z * v.z; q.w += v.w * v.w;
    }
    __shared__ float4 ss[4][64], qq[4][64];
    ss[rs][col] = s; qq[rs][col] = q;
    __syncthreads();
    if (t < 64) {
        float4 S = ss[0][t], Q = qq[0][t];
#pragma unroll
        for (int r = 1; r < 4; r++) {
            float4 a = ss[r][t], b2 = qq[r][t];
            S.x += a.x; S.y += a.y; S.z += a.z; S.w += a.w;
            Q.x += b2.x; Q.y += b2.y; Q.z += b2.z; Q.w += b2.w;
        }
        ((float4*)(ws + OFF_PSUM))[(b * NCHUNK + c) * 64 + t] = S;
        ((float4*)(ws + OFF_PSUMSQ))[(b * NCHUNK + c) * 64 + t] = Q;
    }
}

__global__ __launch_bounds__(256) void k_finalize(float* __restrict__ ws) {
    int b = blockIdx.x, d = threadIdx.x;
    float s = 0.f, q = 0.f;
#pragma unroll
    for (int c = 0; c < NCHUNK; c++) {
        s += ws[OFF_PSUM + (b * NCHUNK + c) * DIM + d];
        q += ws[OFF_PSUMSQ + (b * NCHUNK + c) * DIM + d];
    }
    float mean = s * (1.f / NN);
    float var = q * (1.f / NN) - mean * mean;
    float sd = sqrtf(fmaxf(var, 0.f));
    ws[OFF_MEANB + b * DIM + d] = mean;
    ws[OFF_STDB + b * DIM + d] = sd;
}

#define RS_STEP(half)                                                   \
    {                                                                   \
        bool hi = (sub & half) != 0;                                    \
        _Pragma("unroll")                                               \
        for (int j = 0; j < half; j++) {                                \
            float send = hi ? am[j] : am[j + half];                     \
            float keep = hi ? am[j + half] : am[j];                     \
            am[j] = keep + __shfl_xor(send, half, 16);                  \
            send = hi ? as[j] : as[j + half];                           \
            keep = hi ? as[j + half] : as[j];                           \
            as[j] = keep + __shfl_xor(send, half, 16);                  \
        }                                                               \
    }

__global__ __launch_bounds__(256) void k_dist(const float* __restrict__ means,
                                              const float* __restrict__ stds,
                                              float* __restrict__ ws) {
    __shared__ float4 lm[16 * 64], ls[16 * 64];
    int tid = threadIdx.x;
    const float4* gm = (const float4*)(ws + OFF_MEANB);
    const float4* gs = (const float4*)(ws + OFF_STDB);
#pragma unroll
    for (int i = 0; i < 4; i++) {
        lm[i * 256 + tid] = gm[i * 256 + tid];
        ls[i * 256 + tid] = gs[i * 256 + tid];
    }
    __syncthreads();
    int lane = tid & 63, wid = tid >> 6;
    int sub = lane & 15, eg = lane >> 4;
    int e = blockIdx.x * 16 + wid * 4 + eg;
    const float4* mrow = (const float4*)means + (size_t)e * 64;
    const float4* srow = (const float4*)stds + (size_t)e * 64;
    float4 m[4], s[4];
#pragma unroll
    for (int k = 0; k < 4; k++) {
        m[k] = mrow[k * 16 + sub];
        s[k] = srow[k * 16 + sub];
    }
    float am[16], as[16];
#pragma unroll
    for (int b = 0; b < 16; b++) {
        float accm = 0.f, accs = 0.f;
#pragma unroll
        for (int k = 0; k < 4; k++) {
            float4 q = lm[b * 64 + k * 16 + sub];
            float dx = m[k].x - q.x, dy = m[k].y - q.y;
            float dz = m[k].z - q.z, dw = m[k].w - q.w;
            accm += dx * dx + dy * dy + dz * dz + dw * dw;
            q = ls[b * 64 + k * 16 + sub];
            dx = s[k].x - q.x; dy = s[k].y - q.y;
            dz = s[k].z - q.z; dw = s[k].w - q.w;
            accs += dx * dx + dy * dy + dz * dz + dw * dw;
        }
        am[b] = accm; as[b] = accs;
    }
    RS_STEP(8)
    RS_STEP(4)
    RS_STEP(2)
    RS_STEP(1)
    ws[OFF_DS + sub * SZ + e] = sqrtf(am[0]) + sqrtf(as[0]);
}

__global__ __launch_bounds__(256) void k_topk(float* __restrict__ ws) {
    int b = blockIdx.x, tid = threadIdx.x;
    const float* ds = ws + OFF_DS + b * SZ;
    __shared__ float red[256];
    __shared__ int hist[256], cum[256];
    __shared__ float sh_lo, sh_sc;
    __shared__ int sh_T, sh_cnt;
    __shared__ float candV[1024];
    __shared__ int candI[1024];

    // one global pass: 64 values per thread held in registers
    float v[64];
#pragma unroll
    for (int i = 0; i < 64; i++) v[i] = ds[i * 256 + tid];

    float mn = v[0], mx = v[0];
#pragma unroll
    for (int i = 1; i < 64; i++) { mn = fminf(mn, v[i]); mx = fmaxf(mx, v[i]); }
    red[tid] = mn;
    __syncthreads();
    for (int off = 128; off > 0; off >>= 1) {
        if (tid < off) red[tid] = fminf(red[tid], red[tid + off]);
        __syncthreads();
    }
    if (tid == 0) sh_lo = red[0];
    __syncthreads();
    red[tid] = mx;
    __syncthreads();
    for (int off = 128; off > 0; off >>= 1) {
        if (tid < off) red[tid] = fmaxf(red[tid], red[tid + off]);
        __syncthreads();
    }
    if (tid == 0) {
        sh_sc = 255.0f / fmaxf(red[0] - sh_lo, 1e-20f);
        sh_cnt = 0;
    }
    hist[tid] = 0;
    __syncthreads();

    float lo = sh_lo, sc = sh_sc;
    int bin[64];
#pragma unroll
    for (int i = 0; i < 64; i++) {
        int bi = (int)((v[i] - lo) * sc);
        bin[i] = min(max(bi, 0), 255);
        atomicAdd(&hist[bin[i]], 1);
    }
    __syncthreads();

    cum[tid] = hist[tid];
    __syncthreads();
    for (int off = 1; off < 256; off <<= 1) {
        int t2 = (tid >= off) ? cum[tid - off] : 0;
        __syncthreads();
        cum[tid] += t2;
        __syncthreads();
    }
    if (cum[tid] >= TOPK && (tid == 0 || cum[tid - 1] < TOPK)) sh_T = tid;
    __syncthreads();
    int T = sh_T;

#pragma unroll
    for (int i = 0; i < 64; i++) {
        if (bin[i] <= T) {
            int p = atomicAdd(&sh_cnt, 1);
            if (p < 1024) { candV[p] = v[i]; candI[p] = i * 256 + tid; }
        }
    }
    __syncthreads();
    int cnt = min(sh_cnt, 1024);

    // exact parallel rank-count selection; rank unique via (bits,idx) key
    float* topd = ws + OFF_TOPD + b * 64;
    int* topi = (int*)(ws + OFF_TOPI) + b * 64;
    for (int p = tid; p < cnt; p += 256) {
        unsigned long long kp =
            ((unsigned long long)__float_as_uint(candV[p]) << 32) | (unsigned int)candI[p];
        int rank = 0;
        for (int q = 0; q < cnt; q++) {
            unsigned long long kq =
                ((unsigned long long)__float_as_uint(candV[q]) << 32) | (unsigned int)candI[q];
            rank += (kq < kp) ? 1 : 0;
        }
        if (rank < TOPK) {
            topd[rank] = candV[p];
            topi[rank] = candI[p];
        }
    }
}

__global__ __launch_bounds__(256) void k_goal(const float* __restrict__ means,
                                              const float* __restrict__ stds,
                                              const float* __restrict__ t1p,
                                              const float* __restrict__ t2p,
                                              float* __restrict__ ws) {
    int b = blockIdx.x, d = threadIdx.x;
    float t1 = t1p[0], t2 = t2p[0];
    const float* topd = ws + OFF_TOPD + b * 64;
    const int* topi = (const int*)(ws + OFF_TOPI) + b * 64;
    float sum = 0.f;
#pragma unroll 10
    for (int r = 0; r < TOPK; r++) sum += expf(-t1 * topd[r]);
    float inv = 1.f / sum;
    float mg = 0.f, sg = 0.f;
#pragma unroll 5
    for (int r = 0; r < TOPK; r++) {
        float w = expf(-t1 * topd[r]) * inv;
        int idx = topi[r];
        mg += w * means[(size_t)idx * DIM + d];
        sg += w * stds[(size_t)idx * DIM + d];
    }
    float mean = ws[OFF_MEANB + b * DIM + d];
    float sd = ws[OFF_STDB + b * DIM + d];
    float lerp = 1.f / (1.f + expf(-t2));
    float mf = lerp * mg + (1.f - lerp) * mean;
    float sf = lerp * sg + (1.f - lerp) * sd;
    float A = sf / sd;
    float C = mf - A * mean;
    ws[OFF_A + b * DIM + d] = A;
    ws[OFF_C + b * DIM + d] = C;
}

__global__ __launch_bounds__(256) void k_apply(const float* __restrict__ x,
                                               const float* __restrict__ ws,
                                               float* __restrict__ out) {
    int f4 = blockIdx.x * 256 + threadIdx.x;
    int b = f4 >> 17;
    int d4 = f4 & 63;
    float4 xv = ((const float4*)x)[f4];
    float4 a = ((const float4*)(ws + OFF_A))[b * 64 + d4];
    float4 c = ((const float4*)(ws + OFF_C))[b * 64 + d4];
    float4 o;
    o.x = fmaf(a.x, xv.x, c.x);
    o.y = fmaf(a.y, xv.y, c.y);
    o.z = fmaf(a.z, xv.z, c.z);
    o.w = fmaf(a.w, xv.w, c.w);
    ((float4*)out)[f4] = o;
}

extern "C" void kernel_launch(void* const* d_in, const int* in_sizes, int n_in,
                              void* d_out, int out_size, void* d_ws, size_t ws_size,
                              hipStream_t stream) {
    const float* x = (const float*)d_in[0];
    const float* means = (const float*)d_in[1];
    const float* stds = (const float*)d_in[2];
    const float* t1 = (const float*)d_in[3];
    const float* t2 = (const float*)d_in[4];
    float* out = (float*)d_out;
    float* ws = (float*)d_ws;

    k_partial<<<dim3(NCHUNK, B), 256, 0, stream>>>(x, ws);
    k_finalize<<<B, 256, 0, stream>>>(ws);
    k_dist<<<SZ / 16, 256, 0, stream>>>(means, stds, ws);
    k_topk<<<B, 256, 0, stream>>>(ws);
    k_goal<<<B, 256, 0, stream>>>(means, stds, t1, t2, ws);
    k_apply<<<(B * NN * DIM / 4) / 256, 256, 0, stream>>>(x, ws, out);
}